// Round 5
// baseline (996.740 us; speedup 1.0000x reference)
//
#include <hip/hip_runtime.h>
#include <hip/hip_bf16.h>

// MultiHeadAttention: x (8,16,2048,128) fp32, Q=K=V=x per (b,s) head.
// R5: 64 q-rows per wave (2 q-tiles) -> each K/V LDS fragment feeds 2 MFMAs,
// halving LDS-read demand. Streams per-ut (32-u slice) to cap VGPR liveness.
// Pre-pass bf16 images + global_load_lds double-buffer retained from R4.

#define NSEQ   2048
#define DIM    128
#define KVBLK  64
#define TILES  (NSEQ / KVBLK)       // 32
#define IMG    (KVBLK * DIM)        // 8192 shorts = 16 KB per image
// EC = (1/512) * log2(e): exp(s/512) == exp2(s*EC); folded into Q.
#define EC (1.44269504088896f / 512.0f)

typedef short s8v __attribute__((ext_vector_type(8)));
typedef float f4   __attribute__((ext_vector_type(4)));
typedef float f16v __attribute__((ext_vector_type(16)));
typedef unsigned int u2 __attribute__((ext_vector_type(2)));
typedef unsigned int u4 __attribute__((ext_vector_type(4)));

typedef __attribute__((address_space(1))) const void glob_t;
typedef __attribute__((address_space(3))) void lds_t;

__device__ __forceinline__ unsigned pk2(float a, float b) {
    union { __hip_bfloat162 h; unsigned u; } c;
    c.h = __float22bfloat162_rn(make_float2(a, b));
    return c.u;
}
__device__ __forceinline__ int swz(int r) { return ((r & 7) ^ ((r >> 3) & 7)) << 3; }

// ---------------- pre-pass: x -> bf16 swizzled images in ws ----------------
__global__ __launch_bounds__(256)
void prepass(const float* __restrict__ x, short* __restrict__ wsK,
             short* __restrict__ wsV) {
    const int b = blockIdx.x;                       // head*32 + tile
    const float* src = x + (size_t)b * IMG;
    short* dK = wsK + (size_t)b * IMG;
    short* dV = wsV + (size_t)b * IMG;
    const int rw = threadIdx.x >> 4;
    const int cg = threadIdx.x & 15;

    f4 ld[8];
    const float* s = src + (size_t)(4 * rw) * DIM + 8 * cg;
#pragma unroll
    for (int i = 0; i < 4; ++i) {
        ld[2*i]   = *(const f4*)(s + i * DIM);
        ld[2*i+1] = *(const f4*)(s + i * DIM + 4);
    }
#pragma unroll
    for (int i = 0; i < 4; ++i) {                   // K image rows
        const int r = 4 * rw + i;
        u4 kv = { pk2(ld[2*i][0],   ld[2*i][1]),   pk2(ld[2*i][2],   ld[2*i][3]),
                  pk2(ld[2*i+1][0], ld[2*i+1][1]), pk2(ld[2*i+1][2], ld[2*i+1][3]) };
        *(u4*)&dK[(r * DIM + 8 * cg) ^ swz(r)] = kv;
    }
#pragma unroll
    for (int j = 0; j < 8; ++j) {                   // Vt image rows
        const int d  = 8 * cg + j;
        const int hi = j >> 2, jj = j & 3;
        u2 vv = { pk2(ld[0 + hi][jj], ld[2 + hi][jj]),
                  pk2(ld[4 + hi][jj], ld[6 + hi][jj]) };
        *(u2*)&dV[(d * KVBLK + 4 * rw) ^ swz(d)] = vv;
    }
}

// ---------------- main kernel: 64 q-rows/wave, dbuf global_load_lds ----------------
__global__ __launch_bounds__(256, 2)
void attn_lds64(const float* __restrict__ x, const short* __restrict__ wsK,
                const short* __restrict__ wsV, float* __restrict__ out) {
    const int bid  = blockIdx.x;                    // 1024 blocks
    const int wg   = (bid & 7) * 128 + (bid >> 3);  // XCD swizzle (1024 % 8 == 0)
    const int head = wg >> 3;                       // 8 q-blocks of 256 rows
    const int qb   = wg & 7;

    const float* __restrict__ xh = x   + (size_t)head * (NSEQ * DIM);
    float* __restrict__       oh = out + (size_t)head * (NSEQ * DIM);
    const short* gK = wsK + (size_t)head * TILES * IMG;
    const short* gV = wsV + (size_t)head * TILES * IMG;

    const int tid  = threadIdx.x;
    const int lane = tid & 63;
    const int wave = tid >> 6;
    const int l31  = lane & 31;
    const int h    = lane >> 5;

    __shared__ __align__(16) short sK [2][IMG];   // 32 KB
    __shared__ __align__(16) short sVt[2][IMG];   // 32 KB

    // ---- Q frags (x * EC, bf16): 2 q-tiles of 32 rows ----
    const int qw0 = qb * 256 + wave * 64;
    s8v Qf[2][8];
#pragma unroll
    for (int qt = 0; qt < 2; ++qt) {
        const float* qp = xh + (size_t)(qw0 + qt * 32 + l31) * DIM + 8 * h;
#pragma unroll
        for (int ks = 0; ks < 8; ++ks) {
            f4 a = *(const f4*)(qp + ks * 16);
            f4 b = *(const f4*)(qp + ks * 16 + 4);
            u4 q = { pk2(a[0] * EC, a[1] * EC), pk2(a[2] * EC, a[3] * EC),
                     pk2(b[0] * EC, b[1] * EC), pk2(b[2] * EC, b[3] * EC) };
            Qf[qt][ks] = *(s8v*)&q;
        }
    }

    f16v accO[2][4];
#pragma unroll
    for (int qt = 0; qt < 2; ++qt)
#pragma unroll
        for (int dt = 0; dt < 4; ++dt) accO[qt][dt] = (f16v)(0.f);
    float lsum[2] = {0.f, 0.f};

    const int so = wave * 512 + lane * 8;   // per-lane short offset within image
    auto stage = [&](int b, int t) {
        const short* srcK = gK + (size_t)t * IMG + so;
        const short* srcV = gV + (size_t)t * IMG + so;
#pragma unroll
        for (int i = 0; i < 4; ++i) {
            __builtin_amdgcn_global_load_lds((glob_t*)(srcK + i * 2048),
                (lds_t*)&sK[b][wave * 512 + i * 2048], 16, 0, 0);
            __builtin_amdgcn_global_load_lds((glob_t*)(srcV + i * 2048),
                (lds_t*)&sVt[b][wave * 512 + i * 2048], 16, 0, 0);
        }
    };

    stage(0, 0);
    __syncthreads();
    int buf = 0;

    for (int t = 0; t < TILES; ++t) {
        if (t + 1 < TILES) stage(buf ^ 1, t + 1);

#pragma unroll
        for (int ut = 0; ut < 2; ++ut) {
            // ---- QK^T (swapped): accS[qt][r] = S^T[ut*32 + u_loc][q] * EC ----
            f16v accS[2];
            accS[0] = (f16v)(0.f); accS[1] = (f16v)(0.f);
            {
                const int r    = ut * 32 + l31;
                const int base = r * DIM + 8 * h;
                const int sz   = swz(r);
                __builtin_amdgcn_s_setprio(1);
#pragma unroll
                for (int ks = 0; ks < 8; ++ks) {
                    s8v Kf = *(const s8v*)&sK[buf][(base + ks * 16) ^ sz];
                    accS[0] = __builtin_amdgcn_mfma_f32_32x32x16_bf16(
                        Kf, Qf[0][ks], accS[0], 0, 0, 0);
                    accS[1] = __builtin_amdgcn_mfma_f32_32x32x16_bf16(
                        Kf, Qf[1][ks], accS[1], 0, 0, 0);
                }
                __builtin_amdgcn_s_setprio(0);
            }

            // ---- softmax numerator (max-free) + T12 pack, per q-tile ----
            s8v Pf[2][2];
#pragma unroll
            for (int qt = 0; qt < 2; ++qt) {
                float part = 0.f;
#pragma unroll
                for (int r = 0; r < 16; ++r) {
                    float v = __builtin_amdgcn_exp2f(accS[qt][r]);
                    accS[qt][r] = v;
                    part += v;
                }
                lsum[qt] += part;
#pragma unroll
                for (int ksl = 0; ksl < 2; ++ksl) {
#define PP(f) accS[qt][(f) & 15]
                    unsigned pa0 = pk2(PP(8*ksl + 0), PP(8*ksl + 1));
                    unsigned pa1 = pk2(PP(8*ksl + 2), PP(8*ksl + 3));
                    unsigned pb0 = pk2(PP(8*ksl + 4), PP(8*ksl + 5));
                    unsigned pb1 = pk2(PP(8*ksl + 6), PP(8*ksl + 7));
#undef PP
                    auto t0 = __builtin_amdgcn_permlane32_swap(pa0, pb0, false, false);
                    auto t1 = __builtin_amdgcn_permlane32_swap(pa1, pb1, false, false);
                    u4 w = { (unsigned)t0[0], (unsigned)t1[0],
                             (unsigned)t0[1], (unsigned)t1[1] };
                    Pf[qt][ksl] = *(s8v*)&w;
                }
            }

            // ---- PV for this ut: global k-slice = 2*ut + ksl ----
            __builtin_amdgcn_s_setprio(1);
#pragma unroll
            for (int dt = 0; dt < 4; ++dt) {
                const int d    = dt * 32 + l31;
                const int base = d * KVBLK + 8 * h;
                const int sz   = swz(d);
#pragma unroll
                for (int ksl = 0; ksl < 2; ++ksl) {
                    s8v Vf = *(const s8v*)&sVt[buf][(base + (2 * ut + ksl) * 16) ^ sz];
                    accO[0][dt] = __builtin_amdgcn_mfma_f32_32x32x16_bf16(
                        Pf[0][ksl], Vf, accO[0][dt], 0, 0, 0);
                    accO[1][dt] = __builtin_amdgcn_mfma_f32_32x32x16_bf16(
                        Pf[1][ksl], Vf, accO[1][dt], 0, 0, 0);
                }
            }
            __builtin_amdgcn_s_setprio(0);
        }

        __syncthreads();   // drains DMA for next tile; this tile's reads done
        buf ^= 1;
    }

    // ---- epilogue ----
#pragma unroll
    for (int qt = 0; qt < 2; ++qt) {
        const float tot = lsum[qt] + __shfl_xor(lsum[qt], 32);
        const float inv = 1.f / tot;
#pragma unroll
        for (int r = 0; r < 16; ++r) {
            const int q      = (r & 3) + 8 * (r >> 2) + 4 * h;
            const float invq = __shfl(inv, q, 32);
            float* op = oh + (size_t)(qw0 + qt * 32 + q) * DIM + l31;
#pragma unroll
            for (int dt = 0; dt < 4; ++dt)
                op[dt * 32] = accO[qt][dt][r] * invq;
        }
    }
}

// ---------------- fallback (ws too small): R4 no-ws kernel verbatim ----------------
__global__ __launch_bounds__(256, 2)
void attn_fwd_fb(const float* __restrict__ x, float* __restrict__ out) {
    const int bid  = blockIdx.x;
    const int wg   = (bid & 7) * 256 + (bid >> 3);
    const int head = wg >> 4;
    const int qb   = wg & 15;
    const float* __restrict__ xh = x   + (size_t)head * (NSEQ * DIM);
    float* __restrict__       oh = out + (size_t)head * (NSEQ * DIM);
    const int tid  = threadIdx.x;
    const int lane = tid & 63;
    const int wave = tid >> 6;
    const int l31  = lane & 31;
    const int h    = lane >> 5;
    __shared__ __align__(16) short sK [KVBLK * DIM];
    __shared__ __align__(16) short sVt[DIM * KVBLK];
    const int qw0 = qb * 128 + wave * 32;
    s8v Qf[8];
    {
        const float* qp = xh + (size_t)(qw0 + l31) * DIM + 8 * h;
#pragma unroll
        for (int ks = 0; ks < 8; ++ks) {
            f4 a = *(const f4*)(qp + ks * 16);
            f4 b = *(const f4*)(qp + ks * 16 + 4);
            u4 q = { pk2(a[0] * EC, a[1] * EC), pk2(a[2] * EC, a[3] * EC),
                     pk2(b[0] * EC, b[1] * EC), pk2(b[2] * EC, b[3] * EC) };
            Qf[ks] = *(s8v*)&q;
        }
    }
    f16v accO[4];
#pragma unroll
    for (int dt = 0; dt < 4; ++dt) accO[dt] = (f16v)(0.f);
    float lsum = 0.f;
    const int rw = tid >> 4;
    const int cg = tid & 15;
    f4 ld[8];
    {
        const float* s = xh + (size_t)(4 * rw) * DIM + 8 * cg;
#pragma unroll
        for (int i = 0; i < 4; ++i) {
            ld[2*i]   = *(const f4*)(s + i * DIM);
            ld[2*i+1] = *(const f4*)(s + i * DIM + 4);
        }
    }
    for (int kv0 = 0; kv0 < NSEQ; kv0 += KVBLK) {
#pragma unroll
        for (int i = 0; i < 4; ++i) {
            const int r = 4 * rw + i;
            u4 kv = { pk2(ld[2*i][0],   ld[2*i][1]),   pk2(ld[2*i][2],   ld[2*i][3]),
                      pk2(ld[2*i+1][0], ld[2*i+1][1]), pk2(ld[2*i+1][2], ld[2*i+1][3]) };
            *(u4*)&sK[(r * DIM + 8 * cg) ^ swz(r)] = kv;
        }
#pragma unroll
        for (int j = 0; j < 8; ++j) {
            const int d  = 8 * cg + j;
            const int hi = j >> 2, jj = j & 3;
            u2 vv = { pk2(ld[0 + hi][jj], ld[2 + hi][jj]),
                      pk2(ld[4 + hi][jj], ld[6 + hi][jj]) };
            *(u2*)&sVt[(d * KVBLK + 4 * rw) ^ swz(d)] = vv;
        }
        __syncthreads();
        f16v accS[2];
        accS[0] = (f16v)(0.f); accS[1] = (f16v)(0.f);
        __builtin_amdgcn_s_setprio(1);
#pragma unroll
        for (int ut = 0; ut < 2; ++ut) {
            const int r    = ut * 32 + l31;
            const int base = r * DIM + 8 * h;
            const int sz   = swz(r);
#pragma unroll
            for (int ks = 0; ks < 8; ++ks) {
                s8v Kf = *(const s8v*)&sK[(base + ks * 16) ^ sz];
                accS[ut] = __builtin_amdgcn_mfma_f32_32x32x16_bf16(
                    Kf, Qf[ks], accS[ut], 0, 0, 0);
            }
        }
        __builtin_amdgcn_s_setprio(0);
        if (kv0 + KVBLK < NSEQ) {
            const float* s = xh + (size_t)(kv0 + KVBLK + 4 * rw) * DIM + 8 * cg;
#pragma unroll
            for (int i = 0; i < 4; ++i) {
                ld[2*i]   = *(const f4*)(s + i * DIM);
                ld[2*i+1] = *(const f4*)(s + i * DIM + 4);
            }
        }
        float part = 0.f;
#pragma unroll
        for (int ut = 0; ut < 2; ++ut)
#pragma unroll
            for (int r = 0; r < 16; ++r) {
                float v = __builtin_amdgcn_exp2f(accS[ut][r]);
                accS[ut][r] = v;
                part += v;
            }
        lsum += part;
        s8v Pf[4];
#pragma unroll
        for (int ks = 0; ks < 4; ++ks) {
#define PP(f) accS[(f) >> 4][(f) & 15]
            unsigned pa0 = pk2(PP(8*ks + 0), PP(8*ks + 1));
            unsigned pa1 = pk2(PP(8*ks + 2), PP(8*ks + 3));
            unsigned pb0 = pk2(PP(8*ks + 4), PP(8*ks + 5));
            unsigned pb1 = pk2(PP(8*ks + 6), PP(8*ks + 7));
#undef PP
            auto t0 = __builtin_amdgcn_permlane32_swap(pa0, pb0, false, false);
            auto t1 = __builtin_amdgcn_permlane32_swap(pa1, pb1, false, false);
            u4 w = { (unsigned)t0[0], (unsigned)t1[0], (unsigned)t0[1], (unsigned)t1[1] };
            Pf[ks] = *(s8v*)&w;
        }
        __builtin_amdgcn_s_setprio(1);
#pragma unroll
        for (int dt = 0; dt < 4; ++dt) {
            const int d    = dt * 32 + l31;
            const int base = d * KVBLK + 8 * h;
            const int sz   = swz(d);
#pragma unroll
            for (int ks = 0; ks < 4; ++ks) {
                s8v Vf = *(const s8v*)&sVt[(base + ks * 16) ^ sz];
                accO[dt] = __builtin_amdgcn_mfma_f32_32x32x16_bf16(
                    Pf[ks], Vf, accO[dt], 0, 0, 0);
            }
        }
        __builtin_amdgcn_s_setprio(0);
        __syncthreads();
    }
    const float tot = lsum + __shfl_xor(lsum, 32);
    const float inv = 1.f / tot;
#pragma unroll
    for (int r = 0; r < 16; ++r) {
        const int q      = (r & 3) + 8 * (r >> 2) + 4 * h;
        const float invq = __shfl(inv, q, 32);
        float* op = oh + (size_t)(qw0 + q) * DIM + l31;
#pragma unroll
        for (int dt = 0; dt < 4; ++dt)
            op[dt * 32] = accO[dt][r] * invq;
    }
}

extern "C" void kernel_launch(void* const* d_in, const int* in_sizes, int n_in,
                              void* d_out, int out_size, void* d_ws, size_t ws_size,
                              hipStream_t stream) {
    const float* x = (const float*)d_in[0];
    float* out     = (float*)d_out;
    const size_t need = (size_t)2 * 128 * TILES * IMG * sizeof(short);  // 128 MiB
    if (ws_size >= need) {
        short* wsK = (short*)d_ws;
        short* wsV = wsK + (size_t)128 * TILES * IMG;
        hipLaunchKernelGGL(prepass, dim3(128 * TILES), dim3(256), 0, stream, x, wsK, wsV);
        hipLaunchKernelGGL(attn_lds64, dim3(1024), dim3(256), 0, stream, x, wsK, wsV, out);
    } else {
        hipLaunchKernelGGL(attn_fwd_fb, dim3(2048), dim3(256), 0, stream, x, out);
    }
}

// Round 6
// 353.162 us; speedup vs baseline: 2.8223x; 2.8223x over previous
//
#include <hip/hip_runtime.h>
#include <hip/hip_bf16.h>

// MultiHeadAttention: x (8,16,2048,128) fp32, Q=K=V=x per (b,s) head.
// R6: KVBLK=32 + double-buffer -> 32 KB LDS/block -> 3 blocks/CU (12 waves),
// launch_bounds(256,3), reg budget ~144 (audited). R4 pipe ratios retained.

#define NSEQ   2048
#define DIM    128
#define KVBLK  32
#define TILES  (NSEQ / KVBLK)       // 64
#define IMG    (KVBLK * DIM)        // 4096 shorts = 8 KB per image
// EC = (1/512) * log2(e): exp(s/512) == exp2(s*EC); folded into Q.
#define EC (1.44269504088896f / 512.0f)

typedef short s8v __attribute__((ext_vector_type(8)));
typedef float f4   __attribute__((ext_vector_type(4)));
typedef float f16v __attribute__((ext_vector_type(16)));
typedef unsigned int u2 __attribute__((ext_vector_type(2)));
typedef unsigned int u4 __attribute__((ext_vector_type(4)));

typedef __attribute__((address_space(1))) const void glob_t;
typedef __attribute__((address_space(3))) void lds_t;

__device__ __forceinline__ unsigned pk2(float a, float b) {
    union { __hip_bfloat162 h; unsigned u; } c;
    c.h = __float22bfloat162_rn(make_float2(a, b));
    return c.u;
}
// 32-row-image swizzle (uniform bank spread verified for K-read/V-read/DMA)
__device__ __forceinline__ int swz32k(int r) { return ((r & 7) ^ ((r >> 3) & 3)) << 3; }
// 64-row swizzle (fallback kernel only)
__device__ __forceinline__ int swz(int r) { return ((r & 7) ^ ((r >> 3) & 7)) << 3; }

// ---------------- pre-pass: x -> bf16 swizzled 32-row images in ws ----------------
__global__ __launch_bounds__(256)
void prepass(const float* __restrict__ x, short* __restrict__ wsK,
             short* __restrict__ wsV) {
    const int b = blockIdx.x;                   // 4096 blocks, 64 rows each = 2 tiles
    const float* src = x + (size_t)b * (64 * DIM);
    short* dK = wsK + (size_t)b * 2 * IMG;
    short* dV = wsV + (size_t)b * 2 * IMG;
    const int rw = threadIdx.x >> 4;            // rows 4rw..4rw+3 (same 32-row tile)
    const int cg = threadIdx.x & 15;            // cols 8cg..8cg+7
    const int tile = rw >> 3;                   // 0 or 1
    const int ul   = 4 * (rw & 7);              // local u base within tile

    f4 ld[8];
    const float* s = src + (size_t)(4 * rw) * DIM + 8 * cg;
#pragma unroll
    for (int i = 0; i < 4; ++i) {
        ld[2*i]   = *(const f4*)(s + i * DIM);
        ld[2*i+1] = *(const f4*)(s + i * DIM + 4);
    }
#pragma unroll
    for (int i = 0; i < 4; ++i) {               // K image rows (16B stores)
        const int rl = ul + i;
        u4 kv = { pk2(ld[2*i][0],   ld[2*i][1]),   pk2(ld[2*i][2],   ld[2*i][3]),
                  pk2(ld[2*i+1][0], ld[2*i+1][1]), pk2(ld[2*i+1][2], ld[2*i+1][3]) };
        *(u4*)&dK[tile * IMG + ((rl * DIM + 8 * cg) ^ swz32k(rl))] = kv;
    }
#pragma unroll
    for (int j = 0; j < 8; ++j) {               // Vt image rows (8B stores, u ascending)
        const int d  = 8 * cg + j;
        const int hi = j >> 2, jj = j & 3;
        u2 vv = { pk2(ld[0 + hi][jj], ld[2 + hi][jj]),
                  pk2(ld[4 + hi][jj], ld[6 + hi][jj]) };
        *(u2*)&dV[tile * IMG + ((d * KVBLK + ul) ^ swz32k(d))] = vv;
    }
}

// ---------------- main kernel: 32q/wave, KVBLK=32 dbuf, 3 blocks/CU ----------------
__global__ __launch_bounds__(256, 3)
void attn_k32(const float* __restrict__ x, const short* __restrict__ wsK,
              const short* __restrict__ wsV, float* __restrict__ out) {
    const int bid  = blockIdx.x;                    // 2048 blocks
    const int wg   = (bid & 7) * 256 + (bid >> 3);  // XCD swizzle (2048 % 8 == 0)
    const int head = wg >> 4;
    const int qb   = wg & 15;

    const float* __restrict__ xh = x   + (size_t)head * (NSEQ * DIM);
    float* __restrict__       oh = out + (size_t)head * (NSEQ * DIM);
    const short* gK = wsK + (size_t)head * TILES * IMG;
    const short* gV = wsV + (size_t)head * TILES * IMG;

    const int tid  = threadIdx.x;
    const int lane = tid & 63;
    const int wave = tid >> 6;
    const int l31  = lane & 31;
    const int h    = lane >> 5;

    __shared__ __align__(16) short sK [2][IMG];   // 16 KB
    __shared__ __align__(16) short sVt[2][IMG];   // 16 KB

    // ---- Q frags (x * EC, bf16): B-operand, lane holds Q[qw0+l31][ks*16+8h+j] ----
    const int qw0 = qb * 128 + wave * 32;
    s8v Qf[8];
    {
        const float* qp = xh + (size_t)(qw0 + l31) * DIM + 8 * h;
#pragma unroll
        for (int ks = 0; ks < 8; ++ks) {
            f4 a = *(const f4*)(qp + ks * 16);
            f4 b = *(const f4*)(qp + ks * 16 + 4);
            u4 q = { pk2(a[0] * EC, a[1] * EC), pk2(a[2] * EC, a[3] * EC),
                     pk2(b[0] * EC, b[1] * EC), pk2(b[2] * EC, b[3] * EC) };
            Qf[ks] = *(s8v*)&q;
        }
    }

    f16v accO[4];
#pragma unroll
    for (int dt = 0; dt < 4; ++dt) accO[dt] = (f16v)(0.f);
    float lsum = 0.f;

    // stage one tile (8 KB K + 8 KB V): 2+2 global_load_lds_dwordx4 per thread
    auto stage = [&](int b, int t) {
        const short* srcK = gK + (size_t)t * IMG;
        const short* srcV = gV + (size_t)t * IMG;
        const int off = wave * 1024 + lane * 8;
#pragma unroll
        for (int i = 0; i < 2; ++i) {
            __builtin_amdgcn_global_load_lds((glob_t*)(srcK + off + i * 512),
                (lds_t*)&sK[b][off + i * 512], 16, 0, 0);
            __builtin_amdgcn_global_load_lds((glob_t*)(srcV + off + i * 512),
                (lds_t*)&sVt[b][off + i * 512], 16, 0, 0);
        }
    };

    stage(0, 0);
    __syncthreads();
    int buf = 0;

    for (int t = 0; t < TILES; ++t) {
        if (t + 1 < TILES) stage(buf ^ 1, t + 1);   // DMA into other buffer

        // ---- QK^T (swapped): accS[r] = P-logit[q=l31][u=(r&3)+8*(r>>2)+4h] ----
        f16v accS = (f16v)(0.f);
        {
            const int base = l31 * DIM + 8 * h;
            const int sz   = swz32k(l31);
            __builtin_amdgcn_s_setprio(1);
#pragma unroll
            for (int ks = 0; ks < 8; ++ks) {
                s8v Kf = *(const s8v*)&sK[buf][(base + ks * 16) ^ sz];
                accS = __builtin_amdgcn_mfma_f32_32x32x16_bf16(Kf, Qf[ks], accS, 0, 0, 0);
            }
            __builtin_amdgcn_s_setprio(0);
        }

        // ---- softmax numerator (max-free) ----
        float part = 0.f;
#pragma unroll
        for (int r = 0; r < 16; ++r) {
            float v = __builtin_amdgcn_exp2f(accS[r]);
            accS[r] = v;
            part += v;
        }
        lsum += part;

        // ---- T12: PV A-frags in-register (8 cvt_pk + 4 permlane32_swap) ----
        s8v Pf[2];
#pragma unroll
        for (int ksl = 0; ksl < 2; ++ksl) {
            unsigned pa0 = pk2(accS[8*ksl + 0], accS[8*ksl + 1]);
            unsigned pa1 = pk2(accS[8*ksl + 2], accS[8*ksl + 3]);
            unsigned pb0 = pk2(accS[8*ksl + 4], accS[8*ksl + 5]);
            unsigned pb1 = pk2(accS[8*ksl + 6], accS[8*ksl + 7]);
            auto t0 = __builtin_amdgcn_permlane32_swap(pa0, pb0, false, false);
            auto t1 = __builtin_amdgcn_permlane32_swap(pa1, pb1, false, false);
            u4 w = { (unsigned)t0[0], (unsigned)t1[0], (unsigned)t0[1], (unsigned)t1[1] };
            Pf[ksl] = *(s8v*)&w;
        }

        // ---- PV: accO[dt] += P[q][u] V[u][dt*32+l31] ----
        __builtin_amdgcn_s_setprio(1);
#pragma unroll
        for (int dt = 0; dt < 4; ++dt) {
            const int d    = dt * 32 + l31;
            const int base = d * KVBLK + 8 * h;
            const int sz   = swz32k(d);
#pragma unroll
            for (int ksl = 0; ksl < 2; ++ksl) {
                s8v Vf = *(const s8v*)&sVt[buf][(base + ksl * 16) ^ sz];
                accO[dt] = __builtin_amdgcn_mfma_f32_32x32x16_bf16(
                    Pf[ksl], Vf, accO[dt], 0, 0, 0);
            }
        }
        __builtin_amdgcn_s_setprio(0);

        __syncthreads();   // drains DMA (next tile resident); this tile's reads done
        buf ^= 1;
    }

    // ---- epilogue: cross-half reduce, broadcast 1/sum, store fp32 ----
    const float tot = lsum + __shfl_xor(lsum, 32);
    const float inv = 1.f / tot;
#pragma unroll
    for (int r = 0; r < 16; ++r) {
        const int q      = (r & 3) + 8 * (r >> 2) + 4 * h;
        const float invq = __shfl(inv, q, 32);
        float* op = oh + (size_t)(qw0 + q) * DIM + l31;
#pragma unroll
        for (int dt = 0; dt < 4; ++dt)
            op[dt * 32] = accO[dt][r] * invq;
    }
}

// ---------------- fallback (ws too small): proven no-ws kernel ----------------
__global__ __launch_bounds__(256, 2)
void attn_fwd_fb(const float* __restrict__ x, float* __restrict__ out) {
    const int bid  = blockIdx.x;
    const int wg   = (bid & 7) * 256 + (bid >> 3);
    const int head = wg >> 4;
    const int qb   = wg & 15;
    const float* __restrict__ xh = x   + (size_t)head * (NSEQ * DIM);
    float* __restrict__       oh = out + (size_t)head * (NSEQ * DIM);
    const int tid  = threadIdx.x;
    const int lane = tid & 63;
    const int wave = tid >> 6;
    const int l31  = lane & 31;
    const int h    = lane >> 5;
    __shared__ __align__(16) short sK [64 * DIM];
    __shared__ __align__(16) short sVt[DIM * 64];
    const int qw0 = qb * 128 + wave * 32;
    s8v Qf[8];
    {
        const float* qp = xh + (size_t)(qw0 + l31) * DIM + 8 * h;
#pragma unroll
        for (int ks = 0; ks < 8; ++ks) {
            f4 a = *(const f4*)(qp + ks * 16);
            f4 b = *(const f4*)(qp + ks * 16 + 4);
            u4 q = { pk2(a[0] * EC, a[1] * EC), pk2(a[2] * EC, a[3] * EC),
                     pk2(b[0] * EC, b[1] * EC), pk2(b[2] * EC, b[3] * EC) };
            Qf[ks] = *(s8v*)&q;
        }
    }
    f16v accO[4];
#pragma unroll
    for (int dt = 0; dt < 4; ++dt) accO[dt] = (f16v)(0.f);
    float lsum = 0.f;
    const int rw = tid >> 4;
    const int cg = tid & 15;
    f4 ld[8];
    {
        const float* s = xh + (size_t)(4 * rw) * DIM + 8 * cg;
#pragma unroll
        for (int i = 0; i < 4; ++i) {
            ld[2*i]   = *(const f4*)(s + i * DIM);
            ld[2*i+1] = *(const f4*)(s + i * DIM + 4);
        }
    }
    for (int kv0 = 0; kv0 < NSEQ; kv0 += 64) {
#pragma unroll
        for (int i = 0; i < 4; ++i) {
            const int r = 4 * rw + i;
            u4 kv = { pk2(ld[2*i][0],   ld[2*i][1]),   pk2(ld[2*i][2],   ld[2*i][3]),
                      pk2(ld[2*i+1][0], ld[2*i+1][1]), pk2(ld[2*i+1][2], ld[2*i+1][3]) };
            *(u4*)&sK[(r * DIM + 8 * cg) ^ swz(r)] = kv;
        }
#pragma unroll
        for (int j = 0; j < 8; ++j) {
            const int d  = 8 * cg + j;
            const int hi = j >> 2, jj = j & 3;
            u2 vv = { pk2(ld[0 + hi][jj], ld[2 + hi][jj]),
                      pk2(ld[4 + hi][jj], ld[6 + hi][jj]) };
            *(u2*)&sVt[(d * 64 + 4 * rw) ^ swz(d)] = vv;
        }
        __syncthreads();
        f16v accS[2];
        accS[0] = (f16v)(0.f); accS[1] = (f16v)(0.f);
        __builtin_amdgcn_s_setprio(1);
#pragma unroll
        for (int ut = 0; ut < 2; ++ut) {
            const int r    = ut * 32 + l31;
            const int base = r * DIM + 8 * h;
            const int sz   = swz(r);
#pragma unroll
            for (int ks = 0; ks < 8; ++ks) {
                s8v Kf = *(const s8v*)&sK[(base + ks * 16) ^ sz];
                accS[ut] = __builtin_amdgcn_mfma_f32_32x32x16_bf16(
                    Kf, Qf[ks], accS[ut], 0, 0, 0);
            }
        }
        __builtin_amdgcn_s_setprio(0);
        if (kv0 + 64 < NSEQ) {
            const float* s = xh + (size_t)(kv0 + 64 + 4 * rw) * DIM + 8 * cg;
#pragma unroll
            for (int i = 0; i < 4; ++i) {
                ld[2*i]   = *(const f4*)(s + i * DIM);
                ld[2*i+1] = *(const f4*)(s + i * DIM + 4);
            }
        }
        float part = 0.f;
#pragma unroll
        for (int ut = 0; ut < 2; ++ut)
#pragma unroll
            for (int r = 0; r < 16; ++r) {
                float v = __builtin_amdgcn_exp2f(accS[ut][r]);
                accS[ut][r] = v;
                part += v;
            }
        lsum += part;
        s8v Pf[4];
#pragma unroll
        for (int ks = 0; ks < 4; ++ks) {
#define PP(f) accS[(f) >> 4][(f) & 15]
            unsigned pa0 = pk2(PP(8*ks + 0), PP(8*ks + 1));
            unsigned pa1 = pk2(PP(8*ks + 2), PP(8*ks + 3));
            unsigned pb0 = pk2(PP(8*ks + 4), PP(8*ks + 5));
            unsigned pb1 = pk2(PP(8*ks + 6), PP(8*ks + 7));
#undef PP
            auto t0 = __builtin_amdgcn_permlane32_swap(pa0, pb0, false, false);
            auto t1 = __builtin_amdgcn_permlane32_swap(pa1, pb1, false, false);
            u4 w = { (unsigned)t0[0], (unsigned)t1[0], (unsigned)t0[1], (unsigned)t1[1] };
            Pf[ks] = *(s8v*)&w;
        }
        __builtin_amdgcn_s_setprio(1);
#pragma unroll
        for (int dt = 0; dt < 4; ++dt) {
            const int d    = dt * 32 + l31;
            const int base = d * 64 + 8 * h;
            const int sz   = swz(d);
#pragma unroll
            for (int ks = 0; ks < 4; ++ks) {
                s8v Vf = *(const s8v*)&sVt[(base + ks * 16) ^ sz];
                accO[dt] = __builtin_amdgcn_mfma_f32_32x32x16_bf16(
                    Pf[ks], Vf, accO[dt], 0, 0, 0);
            }
        }
        __builtin_amdgcn_s_setprio(0);
        __syncthreads();
    }
    const float tot = lsum + __shfl_xor(lsum, 32);
    const float inv = 1.f / tot;
#pragma unroll
    for (int r = 0; r < 16; ++r) {
        const int q      = (r & 3) + 8 * (r >> 2) + 4 * h;
        const float invq = __shfl(inv, q, 32);
        float* op = oh + (size_t)(qw0 + q) * DIM + l31;
#pragma unroll
        for (int dt = 0; dt < 4; ++dt)
            op[dt * 32] = accO[dt][r] * invq;
    }
}

extern "C" void kernel_launch(void* const* d_in, const int* in_sizes, int n_in,
                              void* d_out, int out_size, void* d_ws, size_t ws_size,
                              hipStream_t stream) {
    const float* x = (const float*)d_in[0];
    float* out     = (float*)d_out;
    const size_t perImg = (size_t)128 * TILES * IMG;            // shorts
    const size_t need   = 2 * perImg * sizeof(short);           // 128 MiB
    if (ws_size >= need) {
        short* wsK = (short*)d_ws;
        short* wsV = wsK + perImg;
        hipLaunchKernelGGL(prepass, dim3(4096), dim3(256), 0, stream, x, wsK, wsV);
        hipLaunchKernelGGL(attn_k32, dim3(2048), dim3(256), 0, stream, x, wsK, wsV, out);
    } else {
        hipLaunchKernelGGL(attn_fwd_fb, dim3(2048), dim3(256), 0, stream, x, out);
    }
}